// Round 6
// baseline (591.574 us; speedup 1.0000x reference)
//
#include <hip/hip_runtime.h>

// LatentLinearModel: out[i] = dot(U[users[i]], V[jokes[i]]) + a[users[i]] + b[jokes[i]] + g
// K=64 floats/row = 256 B contiguous.
//
// R5 analysis: MLP / ordering / nt-hints all neutral; kernel pinned ~135us.
// Remaining untried lever: working-set partitioning. U(256MB)+V(26MB) > L3
// (256MB), so U's 37% duplicate gathers + V reuse can thrash. R6: 4 passes,
// pass s processes only rows with users[i]>>18 == s -> per-pass working set
// = 64MB U-slice + 26MB V + 8MB idx + 4.4MB biases ~ 102MB, L3-resident.
// Each unique U row fetched from HBM exactly once (166MB floor). Costs only
// 3 extra launches + L3-resident idx re-scans; no atomics, no sort.

constexpr int KV  = 16;   // float4s per 64-float row
constexpr int RPG = 4;    // rows per 16-lane group
constexpr int SLICE_SHIFT = 18;   // 262144-row U slices (4 slices for N=1e6)
constexpr int NSLICES     = 4;

typedef __attribute__((ext_vector_type(4))) float f4_t;
typedef __attribute__((ext_vector_type(4))) int   i4_t;

__global__ __launch_bounds__(256) void latent_linear_kernel(
    const int* __restrict__ users,
    const int* __restrict__ jokes,
    const float* __restrict__ U,
    const float* __restrict__ V,
    const float* __restrict__ a,
    const float* __restrict__ b,
    const float* __restrict__ g,
    float* __restrict__ out,
    int B, int slice)
{
    const int tid  = blockIdx.x * blockDim.x + threadIdx.x;
    const int grp  = tid >> 4;          // 16-lane group id
    const int sub  = tid & 15;          // which float4 of a row
    const int base = grp * RPG;
    if (base >= B) return;

    const f4_t* __restrict__ U4 = reinterpret_cast<const f4_t*>(U);
    const f4_t* __restrict__ V4 = reinterpret_cast<const f4_t*>(V);
    const i4_t* __restrict__ users4 = reinterpret_cast<const i4_t*>(users);
    const i4_t* __restrict__ jokes4 = reinterpret_cast<const i4_t*>(jokes);

    const float g0 = g[0];

    if (base + RPG <= B) {
        const i4_t u4 = users4[grp];    // cacheable: reused across passes
        const i4_t j4 = jokes4[grp];
        const int ui[RPG] = {u4.x, u4.y, u4.z, u4.w};
        const int ji[RPG] = {j4.x, j4.y, j4.z, j4.w};

        // Slice filter: only rows whose U-row lives in this pass's slice.
        bool m[RPG];
#pragma unroll
        for (int r = 0; r < RPG; ++r) m[r] = (((unsigned)ui[r]) >> SLICE_SHIFT) == (unsigned)slice;

        // Issue all matching gathers together (cacheable: dups should hit L3 now).
        f4_t uu[RPG], vv[RPG];
#pragma unroll
        for (int r = 0; r < RPG; ++r) {
            if (m[r]) {
                uu[r] = U4[(size_t)ui[r] * KV + sub];
                vv[r] = V4[(size_t)ji[r] * KV + sub];
            }
        }

        float ab[RPG], bb[RPG];
#pragma unroll
        for (int r = 0; r < RPG; ++r) {
            if (m[r]) { ab[r] = a[ui[r]]; bb[r] = b[ji[r]]; }
        }

#pragma unroll
        for (int r = 0; r < RPG; ++r) {
            if (m[r]) {
                float d = uu[r].x * vv[r].x + uu[r].y * vv[r].y
                        + uu[r].z * vv[r].z + uu[r].w * vv[r].w;
                d += __shfl_down(d, 8, 16);
                d += __shfl_down(d, 4, 16);
                d += __shfl_down(d, 2, 16);
                d += __shfl_down(d, 1, 16);
                if (sub == 0)
                    __builtin_nontemporal_store(d + ab[r] + bb[r] + g0, &out[base + r]);
            }
        }
    } else {
        // tail (not hit for B = 1<<20)
        for (int r = 0; r < RPG && base + r < B; ++r) {
            const int row = base + r;
            const int ui = users[row], ji = jokes[row];
            if ((((unsigned)ui) >> SLICE_SHIFT) != (unsigned)slice) continue;
            const f4_t uu = U4[(size_t)ui * KV + sub];
            const f4_t vv = V4[(size_t)ji * KV + sub];
            float d = uu.x * vv.x + uu.y * vv.y + uu.z * vv.z + uu.w * vv.w;
            d += __shfl_down(d, 8, 16);
            d += __shfl_down(d, 4, 16);
            d += __shfl_down(d, 2, 16);
            d += __shfl_down(d, 1, 16);
            if (sub == 0)
                out[row] = d + a[ui] + b[ji] + g0;
        }
    }
}

extern "C" void kernel_launch(void* const* d_in, const int* in_sizes, int n_in,
                              void* d_out, int out_size, void* d_ws, size_t ws_size,
                              hipStream_t stream)
{
    const int*   users = (const int*)d_in[0];
    const int*   jokes = (const int*)d_in[1];
    const float* U     = (const float*)d_in[2];
    const float* V     = (const float*)d_in[3];
    const float* a     = (const float*)d_in[4];
    const float* b     = (const float*)d_in[5];
    const float* g     = (const float*)d_in[6];
    float*       out   = (float*)d_out;

    const int B = in_sizes[0];              // 1048576 rows
    const int groups = (B + RPG - 1) / RPG;
    const long long threads_total = (long long)groups * 16;
    const int block = 256;
    const int grid = (int)((threads_total + block - 1) / block);

    for (int s = 0; s < NSLICES; ++s)
        latent_linear_kernel<<<grid, block, 0, stream>>>(users, jokes, U, V, a, b, g, out, B, s);
}